// Round 3
// baseline (430.957 us; speedup 1.0000x reference)
//
#include <hip/hip_runtime.h>
#include <stdint.h>

typedef unsigned short ushort_t;
typedef __attribute__((ext_vector_type(8))) short short8;
typedef __attribute__((ext_vector_type(4))) float floatx4;
typedef __attribute__((ext_vector_type(4))) unsigned short ushortx4;
typedef __attribute__((ext_vector_type(8))) unsigned short ushortx8;

#define B_   16
#define CIN  128
#define CH   256
#define HW   96
#define HP   98

// ws layout (bytes)
#define XPAD_ELEMS (B_*HP*HP*CIN)            // bf16 elems
#define HPAD_ELEMS (B_*HP*HP*CH)             // bf16 elems
#define XPAD_OFF 0
#define HPAD_OFF (XPAD_ELEMS*2)
#define W1T_OFF  (HPAD_OFF + HPAD_ELEMS*2)
#define W2T_OFF  (W1T_OFF + 256*1152*2)

__device__ __forceinline__ ushort_t f2bf(float f){
  uint32_t u = __float_as_uint(f);
  u += 0x7FFF + ((u >> 16) & 1);   // RNE
  return (ushort_t)(u >> 16);
}
__device__ __forceinline__ float bf2f(ushort_t h){
  return __uint_as_float(((uint32_t)h) << 16);
}
__device__ __forceinline__ void async_ld16(void* lds, const void* g){
  __builtin_amdgcn_global_load_lds(
      (const __attribute__((address_space(1))) void*)g,
      (__attribute__((address_space(3))) void*)lds, 16, 0, 0);
}

// Zero the 1-px border cells of a padded NHWC tensor. C2 = channels/2 (uint32 words per cell).
__global__ void zero_border(uint32_t* __restrict__ base, int C2){
  int tid = blockIdx.x*256 + threadIdx.x;
  int perimg = 388*C2;
  int total = B_*perimg;
  if (tid >= total) return;
  int b = tid / perimg; int r = tid % perimg;
  int cell = r / C2;    int cu = r % C2;
  int y, x;
  if      (cell < 98)  { y = 0;            x = cell;       }
  else if (cell < 196) { y = 97;           x = cell - 98;  }
  else if (cell < 292) { y = cell - 195;   x = 0;          }
  else                 { y = cell - 291;   x = 97;         }
  base[((b*HP + y)*HP + x)*C2 + cu] = 0u;
}

// NCHW fp32 -> padded NHWC bf16 via LDS transpose. One block = (b, 4 y-rows, 32x, 32c).
__global__ void transform_x(const float* __restrict__ x, ushort_t* __restrict__ xpad){
  __shared__ float lds[32][33];
  int bid = blockIdx.x;              // 4608 = 16 b * 24 yt * 3 xt * 4 ct
  int ct = bid & 3; int xt = (bid>>2) % 3; int yt = (bid/12) % 24; int b = bid/288;
  int c0 = ct*32, x0 = xt*32, y0 = yt*4;
  int t = threadIdx.x;
  for (int yy=0; yy<4; ++yy){
    int y = y0 + yy;
    #pragma unroll
    for (int rep=0; rep<4; ++rep){
      int idx = rep*256 + t;
      int ci = idx >> 5, xj = idx & 31;
      lds[ci][xj] = x[((b*CIN + c0+ci)*HW + y)*HW + x0 + xj];
    }
    __syncthreads();
    int px = t >> 3, quad = t & 7;
    ushortx4 v;
    #pragma unroll
    for (int k=0;k<4;k++) v[k] = f2bf(lds[quad*4+k][px]);
    *(ushortx4*)&xpad[(((b*HP + y+1)*HP) + x0+px+1)*CIN + c0 + quad*4] = v;
    __syncthreads();
  }
}

// w1 [256][128][3][3] fp32 -> w1t [256][1152] bf16, k = tap*128 + c
__global__ void transform_w1(const float* __restrict__ w1, ushort_t* __restrict__ w1t){
  int tid = blockIdx.x*256 + threadIdx.x;   // 294912 exact
  int o = tid / 1152, k = tid - o*1152;
  int tap = k >> 7, c = k & 127;
  w1t[tid] = f2bf(w1[(o*CIN + c)*9 + tap]);
}

// w2 [2][256][3][3] fp32 -> w2t [9][256][2] fp32
__global__ void transform_w2(const float* __restrict__ w2, float* __restrict__ w2t){
  int tid = blockIdx.x*256 + threadIdx.x;
  if (tid >= 4608) return;
  int ch = tid & 1, c = (tid >> 1) & 255, tap = tid >> 9;
  w2t[tid] = w2[(ch*CH + c)*9 + tap];
}

// conv1: implicit GEMM, M=256(out ch) x N=147456(pixels) x K=1152(tap*128+c).
// BM=128, BN=128 (pixel tile 4y x 32x), BK=64. 4 waves, each 64x64 (4x4 frags 16x16x32).
// Round-1 numerics exactly; only blockIdx is XCD-remapped (bijective, 2304%8==0).
__global__ __launch_bounds__(256) void conv1(const ushort_t* __restrict__ xpad,
                                             const ushort_t* __restrict__ w1t,
                                             const float* __restrict__ b1,
                                             ushort_t* __restrict__ hpad){
  __shared__ __align__(16) ushort_t Alds[128*64];
  __shared__ __align__(16) ushort_t Blds[128*64];
  int orig = blockIdx.x;
  int bid = (orig & 7) * 288 + (orig >> 3);   // XCD-aware bijective swizzle
  int mt = bid & 1;
  int nt = bid >> 1;
  int b = nt / 72; int rem = nt % 72;
  int y0 = (rem/3)*4, x0 = (rem - (rem/3)*3)*32;
  int o0 = mt*128;
  int t = threadIdx.x;
  int lane = t & 63, wave = t >> 6;
  int wm = wave >> 1, wn = wave & 1;

  int bgoff[4], agoff[4];
  #pragma unroll
  for (int p=0;p<4;p++){
    int unit = p*256 + t;
    int row = unit >> 3, kk = (unit & 7)*8;   // row: A=out-ch / B=pixel; kk: k-octet
    int ty = row >> 5, tx = row & 31;
    bgoff[p] = ((b*HP + y0+ty)*HP + (x0+tx))*CIN + kk;
    agoff[p] = (o0 + row)*1152 + kk;
  }
  floatx4 acc[4][4];
  #pragma unroll
  for (int i=0;i<4;i++)
    #pragma unroll
    for (int j=0;j<4;j++) acc[i][j] = (floatx4){0.f,0.f,0.f,0.f};

  int r = lane & 15, q = lane >> 4;

  for (int step=0; step<18; ++step){
    int tap = step >> 1, c0 = (step & 1) << 6;
    int dy = tap/3, dx = tap - dy*3;
    int bdelta = (dy*HP + dx)*CIN + c0;
    int adelta = step*64;
    #pragma unroll
    for (int p=0;p<4;p++){
      async_ld16(&Alds[(p*256 + wave*64)*8], &w1t[agoff[p] + adelta]);
      async_ld16(&Blds[(p*256 + wave*64)*8], &xpad[bgoff[p] + bdelta]);
    }
    __syncthreads();   // drains vmcnt -> staged data visible
    #pragma unroll
    for (int kk2=0; kk2<2; ++kk2){
      short8 af[4], bfr[4];
      #pragma unroll
      for (int mf=0; mf<4; ++mf)
        af[mf] = *(const short8*)&Alds[(wm*64 + mf*16 + r)*64 + kk2*32 + q*8];
      #pragma unroll
      for (int nf=0; nf<4; ++nf)
        bfr[nf] = *(const short8*)&Blds[(wn*64 + nf*16 + r)*64 + kk2*32 + q*8];
      #pragma unroll
      for (int mf=0; mf<4; ++mf)
        #pragma unroll
        for (int nf=0; nf<4; ++nf)
          acc[mf][nf] = __builtin_amdgcn_mfma_f32_16x16x32_bf16(af[mf], bfr[nf], acc[mf][nf], 0,0,0);
    }
    __syncthreads();   // protect LDS before next stage overwrites
  }

  // epilogue: +bias, ReLU, bf16, store padded NHWC h
  #pragma unroll
  for (int mf=0; mf<4; ++mf){
    int o = o0 + wm*64 + mf*16 + q*4;
    float bias0 = b1[o], bias1 = b1[o+1], bias2 = b1[o+2], bias3 = b1[o+3];
    #pragma unroll
    for (int nf=0; nf<4; ++nf){
      int n = wn*64 + nf*16 + r;
      int ty = n >> 5, tx = n & 31;
      ushortx4 v;
      v[0] = f2bf(fmaxf(acc[mf][nf][0] + bias0, 0.f));
      v[1] = f2bf(fmaxf(acc[mf][nf][1] + bias1, 0.f));
      v[2] = f2bf(fmaxf(acc[mf][nf][2] + bias2, 0.f));
      v[3] = f2bf(fmaxf(acc[mf][nf][3] + bias3, 0.f));
      *(ushortx4*)&hpad[((b*HP + y0+ty+1)*HP + (x0+tx+1))*CH + o] = v;
    }
  }
}

// conv2: direct 3x3 over bf16 NHWC h. Block = 4y x 32x pixel tile, 2 threads/pixel
// (channel halves), fp32 fmaf, shfl_xor(1) combine.
__global__ __launch_bounds__(256) void conv2(const ushort_t* __restrict__ hpad,
                                             const float* __restrict__ w2t,
                                             const float* __restrict__ b2,
                                             float* __restrict__ out){
  int bid = blockIdx.x;              // 1152 = 16 b * 24 yt * 3 xt
  int b  = bid / 72;  int rem = bid % 72;
  int y0 = (rem / 3) * 4, x0 = (rem % 3) * 32;
  int t = threadIdx.x;
  int half = t & 1;
  int pit = t >> 1;                  // 0..127
  int ty = pit >> 5, tx = pit & 31;
  int y = y0 + ty, x = x0 + tx;
  float a0 = 0.f, a1 = 0.f;
  const ushort_t* base = hpad + ((b*HP + y)*HP + x)*CH + half*128;
  #pragma unroll
  for (int tap=0; tap<9; ++tap){
    int dy = tap/3, dxx = tap - dy*3;
    const ushortx8* hp8 = (const ushortx8*)(base + (dy*HP + dxx)*CH);
    const float* wp = w2t + tap*512 + half*256;
    #pragma unroll 4
    for (int c8=0; c8<16; ++c8){
      ushortx8 hv = hp8[c8];
      #pragma unroll
      for (int i=0;i<8;i++){
        float hf = bf2f(hv[i]);
        a0 = fmaf(hf, wp[(c8*8+i)*2    ], a0);
        a1 = fmaf(hf, wp[(c8*8+i)*2 + 1], a1);
      }
    }
  }
  a0 += __shfl_xor(a0, 1);
  a1 += __shfl_xor(a1, 1);
  int p = y*96 + x;
  float val = (half == 0) ? (a0 + b2[0]) : (a1 + b2[1]);
  out[(b*2 + half)*9216 + p] = val;
}

extern "C" void kernel_launch(void* const* d_in, const int* in_sizes, int n_in,
                              void* d_out, int out_size, void* d_ws, size_t ws_size,
                              hipStream_t stream){
  const float* x  = (const float*)d_in[0];
  const float* w1 = (const float*)d_in[1];
  const float* b1 = (const float*)d_in[2];
  const float* w2 = (const float*)d_in[3];
  const float* b2 = (const float*)d_in[4];
  float* out = (float*)d_out;
  char* ws = (char*)d_ws;
  ushort_t* xpad = (ushort_t*)(ws + XPAD_OFF);
  ushort_t* hpad = (ushort_t*)(ws + HPAD_OFF);
  ushort_t* w1t  = (ushort_t*)(ws + W1T_OFF);
  float*    w2t  = (float*)(ws + W2T_OFF);

  hipLaunchKernelGGL(zero_border, dim3(16*388*64/256),  dim3(256), 0, stream, (uint32_t*)xpad, 64);
  hipLaunchKernelGGL(zero_border, dim3(16*388*128/256), dim3(256), 0, stream, (uint32_t*)hpad, 128);
  hipLaunchKernelGGL(transform_x,  dim3(4608),  dim3(256), 0, stream, x, xpad);
  hipLaunchKernelGGL(transform_w1, dim3(1152),  dim3(256), 0, stream, w1, w1t);
  hipLaunchKernelGGL(transform_w2, dim3(18),    dim3(256), 0, stream, w2, w2t);
  hipLaunchKernelGGL(conv1, dim3(2304), dim3(256), 0, stream, xpad, w1t, b1, hpad);
  hipLaunchKernelGGL(conv2, dim3(1152), dim3(256), 0, stream, hpad, w2t, b2, out);
}

// Round 4
// 210.325 us; speedup vs baseline: 2.0490x; 2.0490x over previous
//
#include <hip/hip_runtime.h>
#include <stdint.h>

typedef unsigned short ushort_t;
typedef __attribute__((ext_vector_type(8))) short short8;
typedef __attribute__((ext_vector_type(4))) float floatx4;
typedef __attribute__((ext_vector_type(4))) unsigned short ushortx4;
typedef __attribute__((ext_vector_type(8))) unsigned short ushortx8;

#define B_   16
#define CIN  128
#define CH   256
#define HW   96
#define HP   98

// ws layout (bytes)
#define XPAD_ELEMS (B_*HP*HP*CIN)            // bf16 elems
#define HPAD_ELEMS (B_*HP*HP*CH)             // bf16 elems
#define XPAD_OFF 0
#define HPAD_OFF (XPAD_ELEMS*2)
#define W1T_OFF  (HPAD_OFF + HPAD_ELEMS*2)
#define W2T_OFF  (W1T_OFF + 256*1152*2)

__device__ __forceinline__ ushort_t f2bf(float f){
  uint32_t u = __float_as_uint(f);
  u += 0x7FFF + ((u >> 16) & 1);   // RNE
  return (ushort_t)(u >> 16);
}
__device__ __forceinline__ float bf2f(ushort_t h){
  return __uint_as_float(((uint32_t)h) << 16);
}
__device__ __forceinline__ void async_ld16(void* lds, const void* g){
  __builtin_amdgcn_global_load_lds(
      (const __attribute__((address_space(1))) void*)g,
      (__attribute__((address_space(3))) void*)lds, 16, 0, 0);
}

// Zero the 1-px border cells of a padded NHWC tensor. C2 = channels/2 (uint32 words per cell).
__global__ void zero_border(uint32_t* __restrict__ base, int C2){
  int tid = blockIdx.x*256 + threadIdx.x;
  int perimg = 388*C2;
  int total = B_*perimg;
  if (tid >= total) return;
  int b = tid / perimg; int r = tid % perimg;
  int cell = r / C2;    int cu = r % C2;
  int y, x;
  if      (cell < 98)  { y = 0;            x = cell;       }
  else if (cell < 196) { y = 97;           x = cell - 98;  }
  else if (cell < 292) { y = cell - 195;   x = 0;          }
  else                 { y = cell - 291;   x = 97;         }
  base[((b*HP + y)*HP + x)*C2 + cu] = 0u;
}

// NCHW fp32 -> padded NHWC bf16 via LDS transpose. One block = (b, 4 y-rows, 32x, 32c).
__global__ void transform_x(const float* __restrict__ x, ushort_t* __restrict__ xpad){
  __shared__ float lds[32][33];
  int bid = blockIdx.x;              // 4608 = 16 b * 24 yt * 3 xt * 4 ct
  int ct = bid & 3; int xt = (bid>>2) % 3; int yt = (bid/12) % 24; int b = bid/288;
  int c0 = ct*32, x0 = xt*32, y0 = yt*4;
  int t = threadIdx.x;
  for (int yy=0; yy<4; ++yy){
    int y = y0 + yy;
    #pragma unroll
    for (int rep=0; rep<4; ++rep){
      int idx = rep*256 + t;
      int ci = idx >> 5, xj = idx & 31;
      lds[ci][xj] = x[((b*CIN + c0+ci)*HW + y)*HW + x0 + xj];
    }
    __syncthreads();
    int px = t >> 3, quad = t & 7;
    ushortx4 v;
    #pragma unroll
    for (int k=0;k<4;k++) v[k] = f2bf(lds[quad*4+k][px]);
    *(ushortx4*)&xpad[(((b*HP + y+1)*HP) + x0+px+1)*CIN + c0 + quad*4] = v;
    __syncthreads();
  }
}

// w1 [256][128][3][3] fp32 -> w1t [256][1152] bf16, k = tap*128 + c
__global__ void transform_w1(const float* __restrict__ w1, ushort_t* __restrict__ w1t){
  int tid = blockIdx.x*256 + threadIdx.x;   // 294912 exact
  int o = tid / 1152, k = tid - o*1152;
  int tap = k >> 7, c = k & 127;
  w1t[tid] = f2bf(w1[(o*CIN + c)*9 + tap]);
}

// w2 [2][256][3][3] fp32 -> w2t [9][256][2] fp32
__global__ void transform_w2(const float* __restrict__ w2, float* __restrict__ w2t){
  int tid = blockIdx.x*256 + threadIdx.x;
  if (tid >= 4608) return;
  int ch = tid & 1, c = (tid >> 1) & 255, tap = tid >> 9;
  w2t[tid] = w2[(ch*CH + c)*9 + tap];
}

// conv1: implicit GEMM, M=256(out ch) x N=147456(pixels) x K=1152(tap*128+c).
// BM=128, BN=128 (pixel tile 4y x 32x), BK=64. 4 waves, each 64x64 (4x4 frags 16x16x32).
// Round-1 numerics exactly; only blockIdx is XCD-remapped (bijective, 2304%8==0).
__global__ __launch_bounds__(256) void conv1(const ushort_t* __restrict__ xpad,
                                             const ushort_t* __restrict__ w1t,
                                             const float* __restrict__ b1,
                                             ushort_t* __restrict__ hpad){
  __shared__ __align__(16) ushort_t Alds[128*64];
  __shared__ __align__(16) ushort_t Blds[128*64];
  int orig = blockIdx.x;
  int bid = (orig & 7) * 288 + (orig >> 3);   // XCD-aware bijective swizzle
  int mt = bid & 1;
  int nt = bid >> 1;
  int b = nt / 72; int rem = nt % 72;
  int y0 = (rem/3)*4, x0 = (rem - (rem/3)*3)*32;
  int o0 = mt*128;
  int t = threadIdx.x;
  int lane = t & 63, wave = t >> 6;
  int wm = wave >> 1, wn = wave & 1;

  int bgoff[4], agoff[4];
  #pragma unroll
  for (int p=0;p<4;p++){
    int unit = p*256 + t;
    int row = unit >> 3, kk = (unit & 7)*8;   // row: A=out-ch / B=pixel; kk: k-octet
    int ty = row >> 5, tx = row & 31;
    bgoff[p] = ((b*HP + y0+ty)*HP + (x0+tx))*CIN + kk;
    agoff[p] = (o0 + row)*1152 + kk;
  }
  floatx4 acc[4][4];
  #pragma unroll
  for (int i=0;i<4;i++)
    #pragma unroll
    for (int j=0;j<4;j++) acc[i][j] = (floatx4){0.f,0.f,0.f,0.f};

  int r = lane & 15, q = lane >> 4;

  for (int step=0; step<18; ++step){
    int tap = step >> 1, c0 = (step & 1) << 6;
    int dy = tap/3, dx = tap - dy*3;
    int bdelta = (dy*HP + dx)*CIN + c0;
    int adelta = step*64;
    #pragma unroll
    for (int p=0;p<4;p++){
      async_ld16(&Alds[(p*256 + wave*64)*8], &w1t[agoff[p] + adelta]);
      async_ld16(&Blds[(p*256 + wave*64)*8], &xpad[bgoff[p] + bdelta]);
    }
    __syncthreads();   // drains vmcnt -> staged data visible
    #pragma unroll
    for (int kk2=0; kk2<2; ++kk2){
      short8 af[4], bfr[4];
      #pragma unroll
      for (int mf=0; mf<4; ++mf)
        af[mf] = *(const short8*)&Alds[(wm*64 + mf*16 + r)*64 + kk2*32 + q*8];
      #pragma unroll
      for (int nf=0; nf<4; ++nf)
        bfr[nf] = *(const short8*)&Blds[(wn*64 + nf*16 + r)*64 + kk2*32 + q*8];
      #pragma unroll
      for (int mf=0; mf<4; ++mf)
        #pragma unroll
        for (int nf=0; nf<4; ++nf)
          acc[mf][nf] = __builtin_amdgcn_mfma_f32_16x16x32_bf16(af[mf], bfr[nf], acc[mf][nf], 0,0,0);
    }
    __syncthreads();   // protect LDS before next stage overwrites
  }

  // epilogue: +bias, ReLU, bf16, store padded NHWC h
  #pragma unroll
  for (int mf=0; mf<4; ++mf){
    int o = o0 + wm*64 + mf*16 + q*4;
    float bias0 = b1[o], bias1 = b1[o+1], bias2 = b1[o+2], bias3 = b1[o+3];
    #pragma unroll
    for (int nf=0; nf<4; ++nf){
      int n = wn*64 + nf*16 + r;
      int ty = n >> 5, tx = n & 31;
      ushortx4 v;
      v[0] = f2bf(fmaxf(acc[mf][nf][0] + bias0, 0.f));
      v[1] = f2bf(fmaxf(acc[mf][nf][1] + bias1, 0.f));
      v[2] = f2bf(fmaxf(acc[mf][nf][2] + bias2, 0.f));
      v[3] = f2bf(fmaxf(acc[mf][nf][3] + bias3, 0.f));
      *(ushortx4*)&hpad[((b*HP + y0+ty+1)*HP + (x0+tx+1))*CH + o] = v;
    }
  }
}

// conv2: LDS-staged direct 3x3. Block = 8x8 output tile, halo 10x10 cells x 512B
// staged into LDS (51.2 KB) via global_load_lds: LDS dest linear, global SOURCE
// pre-swizzled chunk ^ (cell&7); reads apply the same XOR (both-sides involution).
// Wave = channel quarter (w addresses wave-uniform -> scalar cache); lane = pixel.
__global__ __launch_bounds__(256) void conv2(const ushort_t* __restrict__ hpad,
                                             const float* __restrict__ w2t,
                                             const float* __restrict__ b2,
                                             float* __restrict__ out){
  __shared__ __align__(16) ushort_t hlds[25600];   // 100 cells * 256 ushorts
  __shared__ float part[4][64][2];
  int bid = blockIdx.x;              // 2304 = 16 b * 12 yt * 12 xt
  int b = bid / 144; int rem = bid - b*144;
  int yt = rem / 12, xt = rem - yt*12;
  int y0 = yt*8, x0 = xt*8;          // padded window base = (y0, x0)
  int t = threadIdx.x;
  int wave = t >> 6, lane = t & 63;

  // stage 3200 x 16B chunks, pre-swizzled source
  for (int pass=0; pass<13; ++pass){
    int u = pass*256 + t;
    if (u < 3200){
      int cell = u >> 5, cf = u & 31;
      int hy = cell / 10, hx = cell - hy*10;
      const ushort_t* src = hpad + ((b*HP + y0+hy)*HP + (x0+hx))*CH
                                 + ((cf ^ (cell & 7)) << 3);
      async_ld16(&hlds[(pass*256 + wave*64)*8], src);
    }
  }
  __syncthreads();

  int q = __builtin_amdgcn_readfirstlane(wave);    // channel quarter, provably uniform
  int ty = lane >> 3, tx = lane & 7;
  float a0 = 0.f, a1 = 0.f;
  for (int tap=0; tap<9; ++tap){
    int dy = tap/3, dxx = tap - dy*3;
    int cell = (ty+dy)*10 + (tx+dxx);
    int s = cell & 7;
    const float* wp = w2t + (tap*256 + q*64)*2;    // scalar pointer
    #pragma unroll
    for (int g=0; g<8; ++g){
      int j = q*8 + g;
      ushortx8 hv = *(const ushortx8*)&hlds[cell*256 + ((j ^ s) << 3)];
      #pragma unroll
      for (int i=0;i<8;i++){
        float hf = bf2f(hv[i]);
        a0 = fmaf(hf, wp[(g*8+i)*2    ], a0);
        a1 = fmaf(hf, wp[(g*8+i)*2 + 1], a1);
      }
    }
  }
  part[wave][lane][0] = a0;
  part[wave][lane][1] = a1;
  __syncthreads();
  if (t < 128){
    int sel = t >> 6, pix = t & 63;
    float v = part[0][pix][sel] + part[1][pix][sel]
            + part[2][pix][sel] + part[3][pix][sel] + b2[sel];
    int yy = y0 + (pix >> 3), xx = x0 + (pix & 7);
    out[(b*2 + sel)*9216 + yy*96 + xx] = v;
  }
}

extern "C" void kernel_launch(void* const* d_in, const int* in_sizes, int n_in,
                              void* d_out, int out_size, void* d_ws, size_t ws_size,
                              hipStream_t stream){
  const float* x  = (const float*)d_in[0];
  const float* w1 = (const float*)d_in[1];
  const float* b1 = (const float*)d_in[2];
  const float* w2 = (const float*)d_in[3];
  const float* b2 = (const float*)d_in[4];
  float* out = (float*)d_out;
  char* ws = (char*)d_ws;
  ushort_t* xpad = (ushort_t*)(ws + XPAD_OFF);
  ushort_t* hpad = (ushort_t*)(ws + HPAD_OFF);
  ushort_t* w1t  = (ushort_t*)(ws + W1T_OFF);
  float*    w2t  = (float*)(ws + W2T_OFF);

  hipLaunchKernelGGL(zero_border, dim3(16*388*64/256),  dim3(256), 0, stream, (uint32_t*)xpad, 64);
  hipLaunchKernelGGL(zero_border, dim3(16*388*128/256), dim3(256), 0, stream, (uint32_t*)hpad, 128);
  hipLaunchKernelGGL(transform_x,  dim3(4608),  dim3(256), 0, stream, x, xpad);
  hipLaunchKernelGGL(transform_w1, dim3(1152),  dim3(256), 0, stream, w1, w1t);
  hipLaunchKernelGGL(transform_w2, dim3(18),    dim3(256), 0, stream, w2, w2t);
  hipLaunchKernelGGL(conv1, dim3(2304), dim3(256), 0, stream, xpad, w1t, b1, hpad);
  hipLaunchKernelGGL(conv2, dim3(2304), dim3(256), 0, stream, hpad, w2t, b2, out);
}